// Round 1
// baseline (68.346 us; speedup 1.0000x reference)
//
#include <hip/hip_runtime.h>
#include <stdint.h>

// ---------------- types ----------------
typedef __attribute__((ext_vector_type(8))) short bfrag_t;   // 8 bf16 = 4 VGPR
typedef __attribute__((ext_vector_type(4))) float floatx4;   // MFMA acc

#define NROWS 16384
#define KDIM  512
#define DDIM  128
#define SDIM  32
#define NTOT  288      // 128 xp | 128 u | 32 scores
#define NTILES 18

// ws byte offsets
#define WFRAG_OFF 0                       // bf16 [16kt][18nt][64lane][8] = 294912 B
#define GB_OFF    294912                  // f32 [32][128] = 16384 B
#define BU_OFF    (294912 + 16384)        // f32 [128]
#define BS_OFF    (311296 + 512)          // f32 [32]
#define ACCW_OFF  (311808 + 128)          // f32 [32][128]
#define ACCG_OFF  (311936 + 16384)        // f32 [32][128]

__device__ __forceinline__ unsigned short f2bf(float f) {
    unsigned u = __float_as_uint(f);
    u += 0x7fffu + ((u >> 16) & 1u);
    return (unsigned short)(u >> 16);
}
__device__ __forceinline__ float bf2f(unsigned short h) {
    return __uint_as_float(((unsigned)h) << 16);
}
__device__ __forceinline__ float sigm(float v) {
    return __builtin_amdgcn_rcpf(1.0f + __expf(-v));
}

// ---------------- prep: combined weights (frag layout), gate base, biases ----------------
__global__ __launch_bounds__(128) void prep_kernel(
    const float* __restrict__ memv, const float* __restrict__ w_in,
    const float* __restrict__ b_in, const float* __restrict__ w_gate,
    const float* __restrict__ b_gate, unsigned char* __restrict__ ws)
{
    __shared__ float wrow[128];
    int bid = blockIdx.x, tid = threadIdx.x;
    unsigned short* wfrag = (unsigned short*)(ws + WFRAG_OFF);
    float* gb = (float*)(ws + GB_OFF);
    float* bu = (float*)(ws + BU_OFF);
    float* bs = (float*)(ws + BS_OFF);

    if (bid < 512) {
        int k = bid;
        if (tid < 128) wrow[tid] = w_in[k * 128 + tid];
        __syncthreads();
        for (int n = tid; n < NTOT; n += 128) {
            float v;
            if (n < 128) {
                v = wrow[n];
            } else if (n < 256) {
                int d = n - 128; float acc = 0.f;
                for (int j = 0; j < 128; ++j)
                    acc += wrow[j] * w_gate[(128 + j) * 128 + d];
                v = acc;
            } else {
                int s = n - 256; float acc = 0.f;
                for (int d = 0; d < 128; ++d)
                    acc += wrow[d] * memv[s * 128 + d];
                v = acc;
            }
            int kt = k >> 5, kk = k & 31;
            int lane = (n & 15) | ((kk >> 3) << 4);
            int j = kk & 7, nt = n >> 4;
            wfrag[(((kt * NTILES) + nt) * 64 + lane) * 8 + j] = f2bf(v);
        }
    } else if (bid < 544) {
        int s = bid - 512;
        if (tid < 128) {
            int d = tid;
            float acc = b_gate[d];
            for (int k = 0; k < 128; ++k)
                acc += memv[s * 128 + k] * w_gate[k * 128 + d];
            gb[s * 128 + d] = acc;
        }
    } else {
        if (tid < 128) {
            float acc = 0.f;
            for (int j = 0; j < 128; ++j)
                acc += b_in[j] * w_gate[(128 + j) * 128 + tid];
            bu[tid] = acc;
        }
        if (tid < 32) {
            float acc = 0.f;
            for (int d = 0; d < 128; ++d)
                acc += b_in[d] * memv[tid * 128 + d];
            bs[tid] = acc;
        }
    }
}

// ---------------- main fused kernel: 256 blocks x 512 threads, 64 rows/block ----------------
__global__ __launch_bounds__(512, 2) void main_kernel(
    const float* __restrict__ x, const float* __restrict__ memv,
    const float* __restrict__ ln_g, const float* __restrict__ ln_b,
    const float* __restrict__ b_in, unsigned char* __restrict__ ws,
    float* __restrict__ out)
{
    __shared__ uint4 smem4[4096];                 // 64 KiB
    unsigned char* smem = (unsigned char*)smem4;

    int tid = threadIdx.x;
    int w = tid >> 6, l = tid & 63;
    int row_base_g = blockIdx.x * 64;

    // ===== Phase 1a: LayerNorm -> swizzled bf16 A tile [64][512] =====
    const float4* x4 = (const float4*)x;
    float4 g0 = ((const float4*)ln_g)[l];
    float4 g1 = ((const float4*)ln_g)[l + 64];
    float4 q0 = ((const float4*)ln_b)[l];
    float4 q1 = ((const float4*)ln_b)[l + 64];
    for (int i = 0; i < 8; ++i) {
        int r = w * 8 + i;
        float4 xa = x4[(size_t)(row_base_g + r) * 128 + l];
        float4 xb = x4[(size_t)(row_base_g + r) * 128 + 64 + l];
        float s1 = xa.x + xa.y + xa.z + xa.w + xb.x + xb.y + xb.z + xb.w;
        float s2 = xa.x*xa.x + xa.y*xa.y + xa.z*xa.z + xa.w*xa.w
                 + xb.x*xb.x + xb.y*xb.y + xb.z*xb.z + xb.w*xb.w;
        #pragma unroll
        for (int m = 1; m < 64; m <<= 1) {
            s1 += __shfl_xor(s1, m);
            s2 += __shfl_xor(s2, m);
        }
        float mu = s1 * (1.f / 512.f);
        float var = s2 * (1.f / 512.f) - mu * mu;
        float rs = rsqrtf(var + 1e-5f);
        float ya0 = (xa.x - mu) * rs * g0.x + q0.x;
        float ya1 = (xa.y - mu) * rs * g0.y + q0.y;
        float ya2 = (xa.z - mu) * rs * g0.z + q0.z;
        float ya3 = (xa.w - mu) * rs * g0.w + q0.w;
        float yb0 = (xb.x - mu) * rs * g1.x + q1.x;
        float yb1 = (xb.y - mu) * rs * g1.y + q1.y;
        float yb2 = (xb.z - mu) * rs * g1.z + q1.z;
        float yb3 = (xb.w - mu) * rs * g1.w + q1.w;
        unsigned long long pa =
            (unsigned long long)f2bf(ya0) | ((unsigned long long)f2bf(ya1) << 16) |
            ((unsigned long long)f2bf(ya2) << 32) | ((unsigned long long)f2bf(ya3) << 48);
        unsigned long long pb =
            (unsigned long long)f2bf(yb0) | ((unsigned long long)f2bf(yb1) << 16) |
            ((unsigned long long)f2bf(yb2) << 32) | ((unsigned long long)f2bf(yb3) << 48);
        int sw = (r & 7) << 4;
        *(unsigned long long*)(smem + ((r * 1024 + l * 8) ^ sw)) = pa;
        *(unsigned long long*)(smem + ((r * 1024 + 512 + l * 8) ^ sw)) = pb;
    }
    __syncthreads();

    // ===== Phase 1b: MFMA GEMM  [64 x 512] @ [512 x 288] =====
    int mgrp = w >> 2;            // 0..1 -> rows mgrp*32 .. +32
    int ng = w & 3;               // n-tile group
    int cnt = (ng < 2) ? 5 : 4;
    int nts[5];
    #pragma unroll
    for (int i = 0; i < 4; ++i) nts[i] = ng + i * 4;
    nts[4] = 16 + ng;

    const bfrag_t* wf = (const bfrag_t*)(ws + WFRAG_OFF);
    int swa = (l & 7) << 4;
    int abase = (mgrp * 32 + (l & 15)) * 1024 + ((l >> 4) << 4);

    floatx4 acc[2][5];
    #pragma unroll
    for (int mt = 0; mt < 2; ++mt)
        #pragma unroll
        for (int i = 0; i < 5; ++i)
            acc[mt][i] = (floatx4){0.f, 0.f, 0.f, 0.f};

    bfrag_t acur0, acur1, anxt0, anxt1, bcur[5], bnxt[5];
    acur0 = *(const bfrag_t*)(smem + ((abase + 0) ^ swa));
    acur1 = *(const bfrag_t*)(smem + ((abase + 16384) ^ swa));
    #pragma unroll
    for (int i = 0; i < 5; ++i)
        if (i < cnt) bcur[i] = wf[(0 * NTILES + nts[i]) * 64 + l];

    for (int kt = 0; kt < 16; ++kt) {
        if (kt < 15) {
            int ab = abase + (kt + 1) * 64;
            anxt0 = *(const bfrag_t*)(smem + (ab ^ swa));
            anxt1 = *(const bfrag_t*)(smem + ((ab + 16384) ^ swa));
            #pragma unroll
            for (int i = 0; i < 5; ++i)
                if (i < cnt) bnxt[i] = wf[((kt + 1) * NTILES + nts[i]) * 64 + l];
        }
        #pragma unroll
        for (int i = 0; i < 5; ++i) {
            if (i < cnt) {
                acc[0][i] = __builtin_amdgcn_mfma_f32_16x16x32_bf16(acur0, bcur[i], acc[0][i], 0, 0, 0);
                acc[1][i] = __builtin_amdgcn_mfma_f32_16x16x32_bf16(acur1, bcur[i], acc[1][i], 0, 0, 0);
            }
        }
        acur0 = anxt0; acur1 = anxt1;
        #pragma unroll
        for (int i = 0; i < 5; ++i) bcur[i] = bnxt[i];
    }
    __syncthreads();   // all MFMA reads of A done; A region may be reused

    // ===== Phase 2 LDS layout (overlays A) =====
    unsigned short* xp_l = (unsigned short*)smem;             // bf16 [64][128]
    unsigned short* u_l  = (unsigned short*)(smem + 16384);   // bf16 [64][128]
    float* sc_l  = (float*)(smem + 32768);                    // f32 [64][32]
    float* pr_l  = (float*)(smem + 40960);                    // f32 [64][32]
    float* mem_l = (float*)(smem + 49152);                    // f32 [32][128]

    const float* bu = (const float*)(ws + BU_OFF);
    const float* bs = (const float*)(ws + BS_OFF);

    // epilogue: scatter accumulators (+bias) into LDS
    #pragma unroll
    for (int mt = 0; mt < 2; ++mt) {
        #pragma unroll
        for (int i = 0; i < 5; ++i) {
            if (i < cnt) {
                int n = nts[i] * 16 + (l & 15);
                int rbase = mgrp * 32 + mt * 16 + ((l >> 4) << 2);
                #pragma unroll
                for (int r = 0; r < 4; ++r) {
                    float v = acc[mt][i][r];
                    int row = rbase + r;
                    if (n < 128)      xp_l[row * 128 + n]       = f2bf(v + b_in[n]);
                    else if (n < 256) u_l[row * 128 + (n - 128)] = f2bf(v + bu[n - 128]);
                    else              sc_l[row * 32 + (n - 256)] = v + bs[n - 256];
                }
            }
        }
    }
    // cooperative load of memory into LDS
    for (int i = tid; i < 4096; i += 512) mem_l[i] = memv[i];
    __syncthreads();

    // ===== Phase B1: softmax + read_content (8 rows per wave) =====
    for (int i = 0; i < 8; ++i) {
        int r = w * 8 + i;
        int s = l & 31;
        float sc = sc_l[r * 32 + s];
        float mx = sc;
        #pragma unroll
        for (int m = 1; m < 32; m <<= 1) mx = fmaxf(mx, __shfl_xor(mx, m));
        float e = __expf(sc - mx);
        float sum = e;
        #pragma unroll
        for (int m = 1; m < 32; m <<= 1) sum += __shfl_xor(sum, m);
        float p = e * __builtin_amdgcn_rcpf(sum);
        if (l < 32) pr_l[r * 32 + l] = p;
        float rc0 = 0.f, rc1 = 0.f;
        #pragma unroll 8
        for (int s2 = 0; s2 < 32; ++s2) {
            float pv = pr_l[r * 32 + s2];
            rc0 += pv * mem_l[s2 * 128 + l];
            rc1 += pv * mem_l[s2 * 128 + l + 64];
        }
        out[(size_t)(row_base_g + r) * 128 + l] = rc0;
        out[(size_t)(row_base_g + r) * 128 + l + 64] = rc1;
    }
    __syncthreads();   // all probs visible

    // ===== Phase B2: accumulate avg_gate / avg_write partials (wave owns 4 s-values) =====
    int sbase = w * 4;
    const float* gb = (const float*)(ws + GB_OFF);
    float gbr0[4], gbr1[4];
    float aw0[4] = {0,0,0,0}, aw1[4] = {0,0,0,0};
    float ag0[4] = {0,0,0,0}, ag1[4] = {0,0,0,0};
    #pragma unroll
    for (int si = 0; si < 4; ++si) {
        gbr0[si] = gb[(sbase + si) * 128 + l];
        gbr1[si] = gb[(sbase + si) * 128 + l + 64];
    }
    for (int r = 0; r < 64; ++r) {
        float xv0 = bf2f(xp_l[r * 128 + l]);
        float xv1 = bf2f(xp_l[r * 128 + l + 64]);
        float uv0 = bf2f(u_l[r * 128 + l]);
        float uv1 = bf2f(u_l[r * 128 + l + 64]);
        #pragma unroll
        for (int si = 0; si < 4; ++si) {
            float p = pr_l[r * 32 + sbase + si];
            aw0[si] += p * xv0;
            aw1[si] += p * xv1;
            ag0[si] += sigm(gbr0[si] + uv0);
            ag1[si] += sigm(gbr1[si] + uv1);
        }
    }
    float* accw = (float*)(ws + ACCW_OFF);
    float* accg = (float*)(ws + ACCG_OFF);
    #pragma unroll
    for (int si = 0; si < 4; ++si) {
        __hip_atomic_fetch_add(&accw[(sbase + si) * 128 + l],      aw0[si], __ATOMIC_RELAXED, __HIP_MEMORY_SCOPE_AGENT);
        __hip_atomic_fetch_add(&accw[(sbase + si) * 128 + l + 64], aw1[si], __ATOMIC_RELAXED, __HIP_MEMORY_SCOPE_AGENT);
        __hip_atomic_fetch_add(&accg[(sbase + si) * 128 + l],      ag0[si], __ATOMIC_RELAXED, __HIP_MEMORY_SCOPE_AGENT);
        __hip_atomic_fetch_add(&accg[(sbase + si) * 128 + l + 64], ag1[si], __ATOMIC_RELAXED, __HIP_MEMORY_SCOPE_AGENT);
    }
}

// ---------------- finalize: new_memory ----------------
__global__ __launch_bounds__(256) void fin_kernel(
    const float* __restrict__ memv, const unsigned char* __restrict__ ws,
    float* __restrict__ out2)
{
    int i = blockIdx.x * 256 + threadIdx.x;   // 4096 total
    const float* accw = (const float*)(ws + ACCW_OFF);
    const float* accg = (const float*)(ws + ACCG_OFF);
    float ag = accg[i] * (1.f / 16384.f);
    float aw = accw[i] * (1.f / 16384.f);
    out2[i] = memv[i] * (1.f - ag) + aw * ag;
}

// ---------------- launcher ----------------
extern "C" void kernel_launch(void* const* d_in, const int* in_sizes, int n_in,
                              void* d_out, int out_size, void* d_ws, size_t ws_size,
                              hipStream_t stream)
{
    (void)in_sizes; (void)n_in; (void)out_size; (void)ws_size;
    const float* x      = (const float*)d_in[0];
    const float* memv   = (const float*)d_in[1];
    const float* ln_g   = (const float*)d_in[2];
    const float* ln_b   = (const float*)d_in[3];
    const float* w_in   = (const float*)d_in[4];
    const float* b_in   = (const float*)d_in[5];
    const float* w_gate = (const float*)d_in[6];
    const float* b_gate = (const float*)d_in[7];
    float* out = (float*)d_out;
    unsigned char* ws = (unsigned char*)d_ws;

    hipMemsetAsync(ws + ACCW_OFF, 0, 32768, stream);
    hipLaunchKernelGGL(prep_kernel, dim3(545), dim3(128), 0, stream,
                       memv, w_in, b_in, w_gate, b_gate, ws);
    hipLaunchKernelGGL(main_kernel, dim3(256), dim3(512), 0, stream,
                       x, memv, ln_g, ln_b, b_in, ws, out);
    hipLaunchKernelGGL(fin_kernel, dim3(16), dim3(256), 0, stream,
                       memv, ws, out + 2097152);
}